// Round 12
// baseline (1176.640 us; speedup 1.0000x reference)
//
#include <hip/hip_runtime.h>

// CRF Viterbi decode: B=64, T=1024, K=256.
// emissions [B,T,K] f32, transitions [K,K] f32 (prev->next). out [B,T] f32 tags.
//
// Path A (M 64MB + gidp 8.4MB + bp 16.75MB + maps 256KB + exits 4KB ~ 89.4MB):
//   1. crf_forward_states : WAVE-LOCAL reduction redesign (r11 post-mortem:
//      serial reducer + 2 barriers = ~900 cyc/step overhead). Wave w owns cols
//      16w..16w+15; lane = (col, 64-prev chunk). Full column max in-wave via
//      2 shfl_xor; gid (first 32-prev group attaining max) min-reduced the
//      same way; double-buffered LDS state -> ONE barrier/step.
//   2. crf_bp_gid         : proven r11 (gid-guided 32-prev scan).
//   3. crf_seg_maps / crf_compose / crf_emit : proven segmented chase.
// Path B: forward(no gid) + bp_matrix full scan + chase.  Path C: zero.

#define CRF_B 64
#define CRF_T 1024
#define CRF_K 256
#define NSEG  16
#define SEGLEN 64

// ---------------------------------------------------------------------------
// Forward
// ---------------------------------------------------------------------------

#define LD4(v, p, col) { \
    v.x = trans[(size_t)(p) * CRF_K + (col)]; \
    v.y = trans[(size_t)((p) + 1) * CRF_K + (col)]; \
    v.z = trans[(size_t)((p) + 2) * CRF_K + (col)]; \
    v.w = trans[(size_t)((p) + 3) * CRF_K + (col)]; }

// 4 adds + 2 fused max3 per quad
#define FWD1(j, u, mm) { \
    float4 sv = sp[j]; \
    float a0 = sv.x + u.x; \
    float a1 = sv.y + u.y; \
    float a2 = sv.z + u.z; \
    float a3 = sv.w + u.w; \
    float q  = fmaxf(fmaxf(a0, a1), a2); \
    mm = fmaxf(fmaxf(q, a3), mm); }

__global__ __launch_bounds__(1024, 4) void crf_forward_states(
    const float* __restrict__ em, const float* __restrict__ trans,
    float* __restrict__ M, unsigned char* __restrict__ gidp)
{
    const int b    = blockIdx.x;
    const int tid  = threadIdx.x;
    const int w    = tid >> 6;        // wave 0..15
    const int lane = tid & 63;
    const int a    = lane >> 4;       // prev chunk 0..3 (prevs 64a..64a+63)
    const int li   = lane & 15;
    const int c    = (w << 4) | li;   // this thread's column (0..255)

    // padded double buffer: prev p stored at 68*(p>>6) + (p&63)
    // -> the 4 chunk bases hit disjoint bank sets (68 % 32 = 4): conflict-free
    __shared__ __align__(16) float sbuf[2][272];

    const int p0 = a << 6;
    float4 u0, u1, u2, u3, u4, u5, u6, u7;
    float4 u8, u9, uA, uB, uC, uD, uE, uF;
    LD4(u0, p0 +  0, c) LD4(u1, p0 +  4, c)
    LD4(u2, p0 +  8, c) LD4(u3, p0 + 12, c)
    LD4(u4, p0 + 16, c) LD4(u5, p0 + 20, c)
    LD4(u6, p0 + 24, c) LD4(u7, p0 + 28, c)
    LD4(u8, p0 + 32, c) LD4(u9, p0 + 36, c)
    LD4(uA, p0 + 40, c) LD4(uB, p0 + 44, c)
    LD4(uC, p0 + 48, c) LD4(uD, p0 + 52, c)
    LD4(uE, p0 + 56, c) LD4(uF, p0 + 60, c)

    const float* emb = em + (size_t)b * CRF_T * CRF_K;
    if (tid < CRF_K)
        sbuf[0][68 * (tid >> 6) + (tid & 63)] = emb[tid];   // state[0]=em[0]
    float e_cur = emb[CRF_K + c];                           // em[1][c]
    __syncthreads();

    int pb = 0;
    const int cslot = 68 * (c >> 6) + (c & 63);

    for (int t = 1; t < CRF_T; ++t) {
        float e_next = 0.0f;
        if (t + 1 < CRF_T) e_next = emb[(t + 1) * CRF_K + c];

        const float4* sp = (const float4*)(sbuf[pb] + 68 * a);
        float m_lo = -INFINITY, m_hi = -INFINITY;
        FWD1(0, u0, m_lo) FWD1(1, u1, m_lo) FWD1(2, u2, m_lo) FWD1(3, u3, m_lo)
        FWD1(4, u4, m_lo) FWD1(5, u5, m_lo) FWD1(6, u6, m_lo) FWD1(7, u7, m_lo)
        FWD1( 8, u8, m_hi) FWD1( 9, u9, m_hi) FWD1(10, uA, m_hi) FWD1(11, uB, m_hi)
        FWD1(12, uC, m_hi) FWD1(13, uD, m_hi) FWD1(14, uE, m_hi) FWD1(15, uF, m_hi)

        // in-wave reduction over the 4 chunk-lanes of this column
        float mv = fmaxf(m_lo, m_hi);
        float o1 = __shfl_xor(mv, 16, 64); mv = fmaxf(mv, o1);
        float o2 = __shfl_xor(mv, 32, 64); mv = fmaxf(mv, o2);

        if (gidp) {
            // first 32-prev group attaining the max (exact == on fmax output)
            int cand = 8;
            cand = (m_hi == mv) ? (2 * a + 1) : cand;
            cand = (m_lo == mv) ? (2 * a)     : cand;
            int g1 = __shfl_xor(cand, 16, 64); cand = min(cand, g1);
            int g2 = __shfl_xor(cand, 32, 64); cand = min(cand, g2);
            int gn = __shfl_down(cand, 1, 64);          // odd col's group
            if (a == 0 && (li & 1) == 0)
                gidp[((size_t)t * CRF_B + b) * 128 + (c >> 1)] =
                    (unsigned char)(cand | (gn << 4));
        }

        if (a == 0) {
            sbuf[pb ^ 1][cslot] = mv + e_cur;
            M[((size_t)t * CRF_B + b) * CRF_K + c] = mv;   // PRE-emission max
        }
        __syncthreads();
        pb ^= 1;
        e_cur = e_next;
    }
}

// ---------------------------------------------------------------------------
// bp via gid (proven r11): 512 blocks (b x cg4 x ts2) x 256 thr (4 waves).
// 64KB transposed trans tile; gid byte for next iteration prefetched.
// ---------------------------------------------------------------------------

#define BPG_CHUNK(j) { \
    float4 mm = M4[j]; float4 ee = E4[j]; \
    float s0 = mm.x + ee.x, s1 = mm.y + ee.y; \
    float s2 = mm.z + ee.z, s3 = mm.w + ee.w; \
    float t0v = s_tile[base + 4*(j) + 0][lane]; \
    float t1v = s_tile[base + 4*(j) + 1][lane]; \
    float t2v = s_tile[base + 4*(j) + 2][lane]; \
    float t3v = s_tile[base + 4*(j) + 3][lane]; \
    float v0 = s0 + t0v; if (v0 > best) { best = v0; arg = base + 4*(j); } \
    float v1 = s1 + t1v; if (v1 > best) { best = v1; arg = base + 4*(j) + 1; } \
    float v2 = s2 + t2v; if (v2 > best) { best = v2; arg = base + 4*(j) + 2; } \
    float v3 = s3 + t3v; if (v3 > best) { best = v3; arg = base + 4*(j) + 3; } }

#define BPG_CHUNK0(j) { \
    float4 ee = E4[j]; \
    float t0v = s_tile[base + 4*(j) + 0][lane]; \
    float t1v = s_tile[base + 4*(j) + 1][lane]; \
    float t2v = s_tile[base + 4*(j) + 2][lane]; \
    float t3v = s_tile[base + 4*(j) + 3][lane]; \
    float v0 = ee.x + t0v; if (v0 > best) { best = v0; arg = base + 4*(j); } \
    float v1 = ee.y + t1v; if (v1 > best) { best = v1; arg = base + 4*(j) + 1; } \
    float v2 = ee.z + t2v; if (v2 > best) { best = v2; arg = base + 4*(j) + 2; } \
    float v3 = ee.w + t3v; if (v3 > best) { best = v3; arg = base + 4*(j) + 3; } }

__global__ __launch_bounds__(256) void crf_bp_gid(
    const float* __restrict__ M, const float* __restrict__ em,
    const float* __restrict__ trans, const unsigned char* __restrict__ gidp,
    unsigned char* __restrict__ bp)
{
    const int b    = blockIdx.x >> 3;
    const int cg   = (blockIdx.x >> 1) & 3;
    const int ts   = blockIdx.x & 1;
    const int tid  = threadIdx.x;
    const int lane = tid & 63;
    const int w    = tid >> 6;      // wave 0..3

    __shared__ float s_tile[CRF_K][64];   // 64 KB: s_tile[prev][col]

    const int k0 = cg * 64;
    for (int idx = tid; idx < CRF_K * 64; idx += 256) {
        const int p = idx >> 6, cc = idx & 63;
        s_tile[p][cc] = trans[(size_t)p * CRF_K + k0 + cc];
    }
    __syncthreads();

    const int t_lo = ts * 512;
    const int t_hi = ts ? (CRF_T - 1) : 512;
    const int half = (k0 >> 1) + (lane >> 1);
    const int odd  = lane & 1;

    int t1 = t_lo + w;
    if (t1 >= t_hi) return;
    unsigned char gb = gidp[((size_t)(t1 + 1) * CRF_B + b) * 128 + half];

    for (; t1 < t_hi; t1 += 4) {
        const int tn = t1 + 4;
        unsigned char gb_next = 0;
        if (tn < t_hi)                         // prefetch next gid byte
            gb_next = gidp[((size_t)(tn + 1) * CRF_B + b) * 128 + half];

        const int g    = odd ? ((gb >> 4) & 7) : (gb & 7);
        const int base = g << 5;
        const float4* E4 =
            (const float4*)(em + ((size_t)b * CRF_T + t1) * CRF_K + base);
        float best = -INFINITY; int arg = base;
        if (t1 == 0) {                         // state[0] = em[0]
            BPG_CHUNK0(0) BPG_CHUNK0(1) BPG_CHUNK0(2) BPG_CHUNK0(3)
            BPG_CHUNK0(4) BPG_CHUNK0(5) BPG_CHUNK0(6) BPG_CHUNK0(7)
        } else {
            const float4* M4 =
                (const float4*)(M + ((size_t)t1 * CRF_B + b) * CRF_K + base);
            BPG_CHUNK(0) BPG_CHUNK(1) BPG_CHUNK(2) BPG_CHUNK(3)
            BPG_CHUNK(4) BPG_CHUNK(5) BPG_CHUNK(6) BPG_CHUNK(7)
        }
        bp[((size_t)b * (CRF_T - 1) + t1) * CRF_K + k0 + lane] =
            (unsigned char)arg;
        gb = gb_next;
    }
}

// ---------------------------------------------------------------------------
// Fallback-B backpointers: full-scan bp_matrix (proven), state = M+em.
// ---------------------------------------------------------------------------

__global__ __launch_bounds__(1024, 2) void crf_bp_matrix(
    const float* __restrict__ M, const float* __restrict__ em,
    const float* __restrict__ trans, unsigned char* __restrict__ bp)
{
    const int b   = blockIdx.x >> 4;
    const int seg = blockIdx.x & 15;
    const int tid = threadIdx.x;
    const int g   = tid >> 8;      // 0..3
    const int k   = tid & 255;

    __shared__ __align__(16) float s_row[CRF_K];
    __shared__ float s_pv[4][CRF_K];
    __shared__ int   s_pi[4][CRF_K];

    const int pbase = g * 64;
    float4 tr[16];
#pragma unroll
    for (int i = 0; i < 16; ++i) {
        const int p = pbase + 4 * i;
        tr[i].x = trans[(p + 0) * CRF_K + k];
        tr[i].y = trans[(p + 1) * CRF_K + k];
        tr[i].z = trans[(p + 2) * CRF_K + k];
        tr[i].w = trans[(p + 3) * CRF_K + k];
    }

    const int t_lo = seg * SEGLEN;
    const int t_hi = min(t_lo + SEGLEN, CRF_T - 1);
    unsigned char* bpb = bp + (size_t)b * (CRF_T - 1) * CRF_K;

    for (int t1 = t_lo; t1 < t_hi; ++t1) {
        if (tid < CRF_K) {
            float ev = em[((size_t)b * CRF_T + t1) * CRF_K + tid];
            float sv = ev;
            if (t1 > 0) sv = M[((size_t)t1 * CRF_B + b) * CRF_K + tid] + ev;
            s_row[tid] = sv;
        }
        __syncthreads();

        float best = -INFINITY;
        int   arg  = pbase;
        const float4* spp = (const float4*)(s_row + pbase);
#pragma unroll
        for (int i = 0; i < 16; ++i) {
            float4 st = spp[i];
            const int p = pbase + 4 * i;
            float s0 = st.x + tr[i].x;
            float s1 = st.y + tr[i].y;
            float s2 = st.z + tr[i].z;
            float s3 = st.w + tr[i].w;
            if (s0 > best) { best = s0; arg = p; }
            if (s1 > best) { best = s1; arg = p + 1; }
            if (s2 > best) { best = s2; arg = p + 2; }
            if (s3 > best) { best = s3; arg = p + 3; }
        }
        s_pv[g][k] = best;
        s_pi[g][k] = arg;
        __syncthreads();
        if (tid < CRF_K) {
            float bv = s_pv[0][tid];
            int   ba = s_pi[0][tid];
#pragma unroll
            for (int j = 1; j < 4; ++j) {
                float v = s_pv[j][tid];
                if (v > bv) { bv = v; ba = s_pi[j][tid]; }
            }
            bpb[(size_t)t1 * CRF_K + tid] = (unsigned char)ba;
        }
        __syncthreads();
    }
}

// ---------------------------------------------------------------------------
// Segmented chase (proven): seg_maps -> compose -> emit.
// ---------------------------------------------------------------------------

__global__ __launch_bounds__(256) void crf_seg_maps(
    const unsigned char* __restrict__ bp, unsigned char* __restrict__ maps)
{
    const int b   = blockIdx.x >> 4;
    const int s   = blockIdx.x & 15;
    const int tid = threadIdx.x;
    const int rows = (s == NSEG - 1) ? SEGLEN - 1 : SEGLEN;
    const int r0   = s * SEGLEN;

    __shared__ unsigned char lbp[SEGLEN][CRF_K];   // 16 KB

    const unsigned char* bpb = bp + (size_t)b * (CRF_T - 1) * CRF_K;
    const int nw = rows * 64;
    for (int w = tid; w < nw; w += 256) {
        const int r = w >> 6, cc = w & 63;
        ((unsigned int*)lbp[r])[cc] =
            ((const unsigned int*)(bpb + (size_t)(r0 + r) * CRF_K))[cc];
    }
    __syncthreads();

    int tag = tid;
    for (int j = rows - 1; j >= 0; --j) tag = lbp[j][tag];
    maps[((size_t)b * NSEG + s) * CRF_K + tid] = (unsigned char)tag;
}

__global__ __launch_bounds__(256) void crf_compose(
    const float* __restrict__ M, const float* __restrict__ em,
    const unsigned char* __restrict__ maps,
    int* __restrict__ exits, float* __restrict__ out)
{
    const int b   = blockIdx.x;
    const int tid = threadIdx.x;

    __shared__ float s_wv[4];
    __shared__ int   s_wi[4];

    float v = M[((size_t)(CRF_T - 1) * CRF_B + b) * CRF_K + tid]
            + em[((size_t)b * CRF_T + (CRF_T - 1)) * CRF_K + tid];
    int   i = tid;
#pragma unroll
    for (int off = 32; off >= 1; off >>= 1) {
        float ov = __shfl_xor(v, off, 64);
        int   oi = __shfl_xor(i, off, 64);
        if (ov > v || (ov == v && oi < i)) { v = ov; i = oi; }
    }
    const int lane = tid & 63, wv = tid >> 6;
    if (lane == 0) { s_wv[wv] = v; s_wi[wv] = i; }
    __syncthreads();
    if (tid == 0) {
        float bv = s_wv[0]; int bi = s_wi[0];
#pragma unroll
        for (int w = 1; w < 4; ++w)
            if (s_wv[w] > bv) { bv = s_wv[w]; bi = s_wi[w]; }
        out[(size_t)b * CRF_T + (CRF_T - 1)] = (float)bi;
        int E = bi;
        exits[b * NSEG + NSEG - 1] = E;
        const unsigned char* mb = maps + (size_t)b * NSEG * CRF_K;
        for (int s = NSEG - 1; s >= 1; --s) {
            E = mb[(size_t)s * CRF_K + E];
            exits[b * NSEG + s - 1] = E;
        }
    }
}

__global__ __launch_bounds__(256) void crf_emit(
    const unsigned char* __restrict__ bp, const int* __restrict__ exits,
    float* __restrict__ out)
{
    const int b   = blockIdx.x >> 4;
    const int s   = blockIdx.x & 15;
    const int tid = threadIdx.x;
    const int rows = (s == NSEG - 1) ? SEGLEN - 1 : SEGLEN;
    const int r0   = s * SEGLEN;

    __shared__ unsigned char lbp[SEGLEN][CRF_K];

    const unsigned char* bpb = bp + (size_t)b * (CRF_T - 1) * CRF_K;
    const int nw = rows * 64;
    for (int w = tid; w < nw; w += 256) {
        const int r = w >> 6, cc = w & 63;
        ((unsigned int*)lbp[r])[cc] =
            ((const unsigned int*)(bpb + (size_t)(r0 + r) * CRF_K))[cc];
    }
    __syncthreads();

    int tag = tid;
    const bool win = (tid == exits[b * NSEG + s]);
    for (int j = rows - 1; j >= 0; --j) {
        tag = lbp[j][tag];
        if (win) out[(size_t)b * CRF_T + r0 + j] = (float)tag;
    }
}

__global__ void crf_zero_out(float* __restrict__ out, int n)
{
    int i = blockIdx.x * blockDim.x + threadIdx.x;
    if (i < n) out[i] = 0.0f;
}

// ---------------------------------------------------------------------------

extern "C" void kernel_launch(void* const* d_in, const int* in_sizes, int n_in,
                              void* d_out, int out_size, void* d_ws, size_t ws_size,
                              hipStream_t stream) {
    (void)in_sizes; (void)n_in;
    const float* em    = (const float*)d_in[0];   // [B,T,K]
    const float* trans = (const float*)d_in[1];   // [K,K]
    float* out = (float*)d_out;                   // [B,T]

    const size_t M_bytes     = (size_t)CRF_T * CRF_B * CRF_K * sizeof(float); // 64 MB
    const size_t gid_bytes   = (size_t)CRF_T * CRF_B * 128;                   // 8.4 MB
    const size_t bp_bytes    = (size_t)CRF_B * (CRF_T - 1) * CRF_K;           // 16.75 MB
    const size_t maps_bytes  = (size_t)CRF_B * NSEG * CRF_K;                  // 256 KB
    const size_t exits_bytes = (size_t)CRF_B * NSEG * sizeof(int);            // 4 KB

    char* w = (char*)d_ws;
    if (ws_size >= M_bytes + gid_bytes + bp_bytes + maps_bytes + exits_bytes) {
        float*         M     = (float*)w;            w += M_bytes;
        unsigned char* gidp  = (unsigned char*)w;    w += gid_bytes;
        unsigned char* bp    = (unsigned char*)w;    w += bp_bytes;
        unsigned char* maps  = (unsigned char*)w;    w += maps_bytes;
        int*           exits = (int*)w;

        crf_forward_states<<<CRF_B, 1024, 0, stream>>>(em, trans, M, gidp);
        crf_bp_gid<<<CRF_B * 8, 256, 0, stream>>>(M, em, trans, gidp, bp);
        crf_seg_maps<<<CRF_B * NSEG, 256, 0, stream>>>(bp, maps);
        crf_compose<<<CRF_B, 256, 0, stream>>>(M, em, maps, exits, out);
        crf_emit<<<CRF_B * NSEG, 256, 0, stream>>>(bp, exits, out);
    } else if (ws_size >= M_bytes + bp_bytes + maps_bytes + exits_bytes) {
        float*         M     = (float*)w;            w += M_bytes;
        unsigned char* bp    = (unsigned char*)w;    w += bp_bytes;
        unsigned char* maps  = (unsigned char*)w;    w += maps_bytes;
        int*           exits = (int*)w;

        crf_forward_states<<<CRF_B, 1024, 0, stream>>>(em, trans, M, nullptr);
        crf_bp_matrix<<<CRF_B * NSEG, 1024, 0, stream>>>(M, em, trans, bp);
        crf_seg_maps<<<CRF_B * NSEG, 256, 0, stream>>>(bp, maps);
        crf_compose<<<CRF_B, 256, 0, stream>>>(M, em, maps, exits, out);
        crf_emit<<<CRF_B * NSEG, 256, 0, stream>>>(bp, exits, out);
    } else {
        crf_zero_out<<<(out_size + 255) / 256, 256, 0, stream>>>(out, out_size);
    }
}